// Round 10
// baseline (449.338 us; speedup 1.0000x reference)
//
#include <hip/hip_runtime.h>
#include <hip/hip_bf16.h>
#include <math.h>

#define HEADS 8
#define EPS 1e-5f

typedef __attribute__((ext_vector_type(8))) _Float16 half8;
typedef __attribute__((ext_vector_type(4))) _Float16 half4;
typedef __attribute__((ext_vector_type(2))) _Float16 half2v;
typedef __attribute__((ext_vector_type(4))) float f32x4;

__device__ __forceinline__ unsigned short f2h(float f) {
    union { _Float16 h; unsigned short u; } v;
    v.h = (_Float16)f;
    return v.u;
}

#define PACK_TOTAL 745472
#define PACK_BLOCKS 2912   // PACK_TOTAL / 256

// ---------------- fused setup #1: weight-pack || degree-histogram || pos-stats ----------------
__global__ void k_setup1(const float* __restrict__ W0, const float* __restrict__ W1,
                         const float* __restrict__ W2, const float* __restrict__ W3,
                         const float* __restrict__ W4, const float* __restrict__ W5,
                         unsigned short* __restrict__ Bp,
                         const int* __restrict__ ei, int* __restrict__ deg,
                         const float* __restrict__ pos, float* __restrict__ pstats,
                         int E, int N, int degBlocks) {
    int b = blockIdx.x, tid = threadIdx.x;
    if (b < PACK_BLOCKS) {
        int idx = b * 256 + tid;
        const int CI[6]  = {16, 32, 64, 128, 256, 128};
        const int CO[6]  = {32, 64, 128, 256, 128, 128};
        const int COP[6] = {64, 64, 128, 256, 128, 128};
        const int OFF[7] = {0, 8192, 24576, 90112, 352256, 614400, 745472};
        int L = 0;
        while (idx >= OFF[L + 1]) ++L;
        const float* W = L == 0 ? W0 : L == 1 ? W1 : L == 2 ? W2 : L == 3 ? W3 : L == 4 ? W4 : W5;
        int rel = idx - OFF[L];
        int j = rel & 7;
        int lane = (rel >> 3) & 63;
        int t = rel >> 9;
        int nT = COP[L] >> 4;
        int nt = t % nT, kt = t / nT;
        int kk = kt * 32 + ((lane >> 4) << 3) + j;
        int c  = (nt << 4) + (lane & 15);
        int ci = CI[L], co = CO[L];
        float v = 0.f;
        if (c < co) {
            int h = kk / ci, ko = kk % ci;
            v = W[ko * (HEADS * co) + h * co + c];
        }
        Bp[idx] = f2h(v);
    } else if (b < PACK_BLOCKS + degBlocks) {
        int e = (b - PACK_BLOCKS) * 256 + tid;
        int E2 = E + N;
        if (e < E2) {
            int dst = (e < E) ? ei[E + e] : (e - E);
            atomicAdd(&deg[dst], 1);
        }
    } else {
        int gid = (b - PACK_BLOCKS - degBlocks) * 256 + tid;
        int stride = 64 * 256;
        float s0 = 0, s1 = 0, q0 = 0, q1 = 0;
        for (int i = gid; i < N; i += stride) {
            float a = pos[i * 2], bb = pos[i * 2 + 1];
            s0 += a; s1 += bb; q0 += a * a; q1 += bb * bb;
        }
        __shared__ float red[256][4];
        red[tid][0] = s0; red[tid][1] = s1; red[tid][2] = q0; red[tid][3] = q1;
        __syncthreads();
        for (int off = 128; off > 0; off >>= 1) {
            if (tid < off) {
                red[tid][0] += red[tid + off][0]; red[tid][1] += red[tid + off][1];
                red[tid][2] += red[tid + off][2]; red[tid][3] += red[tid + off][3];
            }
            __syncthreads();
        }
        if (tid == 0) {
            atomicAdd(&pstats[0], red[0][0]); atomicAdd(&pstats[1], red[0][1]);
            atomicAdd(&pstats[2], red[0][2]); atomicAdd(&pstats[3], red[0][3]);
        }
    }
}

__global__ void k_scan(const int* __restrict__ deg, int* __restrict__ row_ptr, int n) {
    __shared__ int part[1024];
    int t = threadIdx.x;
    int chunk = (n + 1023) >> 10;
    int begin = t * chunk;
    int end = begin + chunk;
    if (begin > n) begin = n;
    if (end > n) end = n;
    int s = 0;
    for (int i = begin; i < end; ++i) s += deg[i];
    part[t] = s;
    __syncthreads();
    for (int off = 1; off < 1024; off <<= 1) {
        int v = (t >= off) ? part[t - off] : 0;
        __syncthreads();
        part[t] += v;
        __syncthreads();
    }
    int run = (t == 0) ? 0 : part[t - 1];
    for (int i = begin; i < end; ++i) { row_ptr[i] = run; run += deg[i]; }
    if (t == 1023) row_ptr[n] = part[1023];
}

// ---------------- fused setup #2: CSR-fill || front (bn(pos)++x -> lin0 -> relu -> h0, xu0) ----------------
__global__ void k_setup2(const int* __restrict__ ei, const int* __restrict__ row_ptr,
                         int* __restrict__ fill, int* __restrict__ src_sorted,
                         const float* __restrict__ pos, const float* __restrict__ x,
                         const float* __restrict__ pstats, const float* __restrict__ g0,
                         const float* __restrict__ b0, const float* __restrict__ W,
                         const float* __restrict__ bias, const float* __restrict__ U0,
                         _Float16* __restrict__ out, float* __restrict__ xu0,
                         int E, int N, int fillBlocks) {
    int b = blockIdx.x, tid = threadIdx.x;
    if (b < fillBlocks) {
        int e = b * 256 + tid;
        int E2 = E + N;
        if (e < E2) {
            int srcv, dst;
            if (e < E) { srcv = ei[e]; dst = ei[E + e]; } else { srcv = e - E; dst = srcv; }
            int p = atomicAdd(&fill[dst], 1);
            src_sorted[row_ptr[dst] + p] = srcv;
        }
    } else {
        int i = (b - fillBlocks) * 256 + tid;
        if (i >= N) return;
        float invn = 1.0f / (float)N;
        float in4[4];
        #pragma unroll
        for (int j = 0; j < 2; ++j) {
            float m = pstats[j] * invn;
            float v = pstats[2 + j] * invn - m * m;
            in4[j] = (pos[i * 2 + j] - m) * rsqrtf(v + EPS) * g0[j] + b0[j];
        }
        in4[2] = x[i * 2]; in4[3] = x[i * 2 + 1];
        float o16[16];
        #pragma unroll
        for (int o = 0; o < 16; ++o) {
            float s = bias[o];
            #pragma unroll
            for (int j = 0; j < 4; ++j) s += in4[j] * W[j * 16 + o];
            o16[o] = fmaxf(s, 0.f);
            out[i * 16 + o] = (_Float16)o16[o];
        }
        #pragma unroll
        for (int hh = 0; hh < 8; ++hh) {
            float p = 0.f;
            #pragma unroll
            for (int k = 0; k < 16; ++k) p += o16[k] * U0[k * 8 + hh];
            xu0[i * 8 + hh] = p;
        }
    }
}

// ---- chunked in-wave softmax: lane computes q[8] for edge (base+lane), parks in LDS ----
__device__ __forceinline__ void chunk_softmax(const float* __restrict__ xu,
        const int* __restrict__ srcs, int base, int cnt, int lane,
        float4 xi0, float4 xi1, float4 c0, float4 c1, float dinv,
        float* __restrict__ qrow, int* __restrict__ srow) {
    if (lane < cnt) {
        int s = srcs[base + lane];
        float4 xs0 = *(const float4*)(xu + (size_t)s * 8);
        float4 xs1 = *(const float4*)(xu + (size_t)s * 8 + 4);
        float t[8];
        t[0] = xs0.x - xi0.x + c0.x; t[1] = xs0.y - xi0.y + c0.y;
        t[2] = xs0.z - xi0.z + c0.z; t[3] = xs0.w - xi0.w + c0.w;
        t[4] = xs1.x - xi1.x + c1.x; t[5] = xs1.y - xi1.y + c1.y;
        t[6] = xs1.z - xi1.z + c1.z; t[7] = xs1.w - xi1.w + c1.w;
        float mx = t[0];
        #pragma unroll
        for (int h = 1; h < 8; ++h) mx = fmaxf(mx, t[h]);
        float sum = 0.f;
        #pragma unroll
        for (int h = 0; h < 8; ++h) { t[h] = __expf(t[h] - mx); sum += t[h]; }
        float qs = dinv / sum;
        float4 q0 = {t[0] * qs, t[1] * qs, t[2] * qs, t[3] * qs};
        float4 q1 = {t[4] * qs, t[5] * qs, t[6] * qs, t[7] * qs};
        *(float4*)(qrow + lane * 8) = q0;
        *(float4*)(qrow + lane * 8 + 4) = q1;
        srow[lane] = s;
    }
}

// ---------------- gather (ci>=64): wave per node, fused softmax, x2-unrolled sweep ----------------
template<int V>
__global__ __launch_bounds__(256) void k_gather_big(const _Float16* __restrict__ hin,
        const float* __restrict__ xu, const float* __restrict__ chead,
        const int* __restrict__ row_ptr, const int* __restrict__ srcs,
        unsigned short* __restrict__ S, int n, int ci) {
    __shared__ float qbuf[4][64 * 8];
    __shared__ int   sbuf[4][64];
    int w = threadIdx.x >> 6, lane = threadIdx.x & 63;
    int i = blockIdx.x * 4 + w;
    if (i >= n) return;
    int rp0 = row_ptr[i], rp1 = row_ptr[i + 1];
    float dinv = 1.f / (float)(rp1 - rp0);
    float4 xi0 = *(const float4*)(xu + (size_t)i * 8);
    float4 xi1 = *(const float4*)(xu + (size_t)i * 8 + 4);
    float4 c0 = *(const float4*)chead;
    float4 c1 = *(const float4*)(chead + 4);
    int kb = lane * V;
    float acc[8][V];
    #pragma unroll
    for (int hh = 0; hh < 8; ++hh)
        #pragma unroll
        for (int v = 0; v < V; ++v) acc[hh][v] = 0.f;

    for (int base = rp0; base < rp1; base += 64) {
        int cnt = rp1 - base; if (cnt > 64) cnt = 64;
        chunk_softmax(xu, srcs, base, cnt, lane, xi0, xi1, c0, c1, dinv, qbuf[w], sbuf[w]);
        int j = 0;
        for (; j + 1 < cnt; j += 2) {
            int s0 = sbuf[w][j], s1 = sbuf[w][j + 1];
            const _Float16* h0 = hin + (size_t)s0 * ci + kb;
            const _Float16* h1 = hin + (size_t)s1 * ci + kb;
            float xv0[V], xv1[V];
            if (V == 4) {
                half4 f0 = *(const half4*)h0, f1 = *(const half4*)h1;
                #pragma unroll
                for (int v = 0; v < 4; ++v) { xv0[v] = (float)f0[v]; xv1[v] = (float)f1[v]; }
            } else if (V == 2) {
                half2v f0 = *(const half2v*)h0, f1 = *(const half2v*)h1;
                #pragma unroll
                for (int v = 0; v < 2; ++v) { xv0[v] = (float)f0[v]; xv1[v] = (float)f1[v]; }
            } else { xv0[0] = (float)h0[0]; xv1[0] = (float)h1[0]; }
            const float4* qa = (const float4*)(qbuf[w] + j * 8);
            const float4* qc = (const float4*)(qbuf[w] + (j + 1) * 8);
            float4 qa0 = qa[0], qa1 = qa[1], qb0 = qc[0], qb1 = qc[1];
            float qA[8] = {qa0.x, qa0.y, qa0.z, qa0.w, qa1.x, qa1.y, qa1.z, qa1.w};
            float qB[8] = {qb0.x, qb0.y, qb0.z, qb0.w, qb1.x, qb1.y, qb1.z, qb1.w};
            #pragma unroll
            for (int hh = 0; hh < 8; ++hh)
                #pragma unroll
                for (int v = 0; v < V; ++v)
                    acc[hh][v] += qA[hh] * xv0[v] + qB[hh] * xv1[v];
        }
        if (j < cnt) {
            int s0 = sbuf[w][j];
            const _Float16* h0 = hin + (size_t)s0 * ci + kb;
            float xv0[V];
            if (V == 4) {
                half4 f = *(const half4*)h0;
                for (int v = 0; v < 4; ++v) xv0[v] = (float)f[v];
            } else if (V == 2) {
                half2v f = *(const half2v*)h0;
                for (int v = 0; v < 2; ++v) xv0[v] = (float)f[v];
            } else {
                xv0[0] = (float)h0[0];
            }
            const float4* qa = (const float4*)(qbuf[w] + j * 8);
            float4 qa0 = qa[0], qa1 = qa[1];
            float qA[8] = {qa0.x, qa0.y, qa0.z, qa0.w, qa1.x, qa1.y, qa1.z, qa1.w};
            #pragma unroll
            for (int hh = 0; hh < 8; ++hh)
                #pragma unroll
                for (int v = 0; v < V; ++v) acc[hh][v] += qA[hh] * xv0[v];
        }
    }
    #pragma unroll
    for (int hh = 0; hh < 8; ++hh) {
        unsigned short o[V];
        #pragma unroll
        for (int v = 0; v < V; ++v) o[v] = f2h(acc[hh][v]);
        unsigned short* sp = S + (size_t)i * 8 * ci + hh * ci + kb;
        if (V == 4)      *(ushort4*)sp = *(ushort4*)o;
        else if (V == 2) *(ushort2*)sp = *(ushort2*)o;
        else             sp[0] = o[0];
    }
}

// ---------------- gather (ci=8*V2<=32): lane -> (head, cols), x2-unrolled sweep ----------------
template<int V2>
__global__ __launch_bounds__(256) void k_gather_small(const _Float16* __restrict__ hin,
        const float* __restrict__ xu, const float* __restrict__ chead,
        const int* __restrict__ row_ptr, const int* __restrict__ srcs,
        unsigned short* __restrict__ S, int n) {
    const int ci = 8 * V2;
    __shared__ float qbuf[4][64 * 8];
    __shared__ int   sbuf[4][64];
    int w = threadIdx.x >> 6, lane = threadIdx.x & 63;
    int i = blockIdx.x * 4 + w;
    if (i >= n) return;
    int rp0 = row_ptr[i], rp1 = row_ptr[i + 1];
    float dinv = 1.f / (float)(rp1 - rp0);
    float4 xi0 = *(const float4*)(xu + (size_t)i * 8);
    float4 xi1 = *(const float4*)(xu + (size_t)i * 8 + 4);
    float4 c0 = *(const float4*)chead;
    float4 c1 = *(const float4*)(chead + 4);
    int hh = lane >> 3;
    int kb = (lane & 7) * V2;
    float acc[V2];
    #pragma unroll
    for (int v = 0; v < V2; ++v) acc[v] = 0.f;

    for (int base = rp0; base < rp1; base += 64) {
        int cnt = rp1 - base; if (cnt > 64) cnt = 64;
        chunk_softmax(xu, srcs, base, cnt, lane, xi0, xi1, c0, c1, dinv, qbuf[w], sbuf[w]);
        int j = 0;
        for (; j + 1 < cnt; j += 2) {
            int s0 = sbuf[w][j], s1 = sbuf[w][j + 1];
            const _Float16* h0 = hin + (size_t)s0 * ci + kb;
            const _Float16* h1 = hin + (size_t)s1 * ci + kb;
            float xv0[V2], xv1[V2];
            if (V2 == 4) {
                half4 f0 = *(const half4*)h0, f1 = *(const half4*)h1;
                #pragma unroll
                for (int v = 0; v < 4; ++v) { xv0[v] = (float)f0[v]; xv1[v] = (float)f1[v]; }
            } else {
                half2v f0 = *(const half2v*)h0, f1 = *(const half2v*)h1;
                #pragma unroll
                for (int v = 0; v < 2; ++v) { xv0[v] = (float)f0[v]; xv1[v] = (float)f1[v]; }
            }
            float q0 = qbuf[w][j * 8 + hh];
            float q1 = qbuf[w][(j + 1) * 8 + hh];
            #pragma unroll
            for (int v = 0; v < V2; ++v) acc[v] += q0 * xv0[v] + q1 * xv1[v];
        }
        if (j < cnt) {
            int s0 = sbuf[w][j];
            const _Float16* h0 = hin + (size_t)s0 * ci + kb;
            float xv0[V2];
            if (V2 == 4) {
                half4 f = *(const half4*)h0;
                for (int v = 0; v < 4; ++v) xv0[v] = (float)f[v];
            } else {
                half2v f = *(const half2v*)h0;
                for (int v = 0; v < 2; ++v) xv0[v] = (float)f[v];
            }
            float q0 = qbuf[w][j * 8 + hh];
            #pragma unroll
            for (int v = 0; v < V2; ++v) acc[v] += q0 * xv0[v];
        }
    }
    unsigned short o[V2];
    #pragma unroll
    for (int v = 0; v < V2; ++v) o[v] = f2h(acc[v]);
    unsigned short* sp = S + (size_t)i * 8 * ci + hh * ci + kb;
    if (V2 == 4) *(ushort4*)sp = *(ushort4*)o;
    else         *(ushort2*)sp = *(ushort2*)o;
}

// ---------------- MFMA fp16 GEMM + fused BN-stats ----------------
__global__ __launch_bounds__(256) void k_gemm_stats(const unsigned short* __restrict__ A,
        const unsigned short* __restrict__ Bp, float* __restrict__ z,
        float* __restrict__ stats, int M, int K, int co, int nTtot) {
    int tid = threadIdx.x;
    int w = tid >> 6, lane = tid & 63;
    int quad = lane >> 4, l16 = lane & 15;
    int m0 = blockIdx.x * 64;
    int n0 = blockIdx.y * 64;
    int nt0 = n0 >> 4;
    int m = m0 + w * 16 + l16;
    int mc = m < M ? m : M - 1;
    const half8* Ap = (const half8*)(A + (size_t)mc * K) + quad;
    const half8* Bb = (const half8*)Bp;
    f32x4 acc[4] = {};
    int nsteps = K >> 5;
    for (int ks = 0; ks < nsteps; ++ks) {
        half8 a = Ap[ks * 4];
        long bbase = ((long)ks * nTtot + nt0) * 64 + lane;
        #pragma unroll
        for (int ct = 0; ct < 4; ++ct) {
            half8 b = Bb[bbase + ct * 64];
            acc[ct] = __builtin_amdgcn_mfma_f32_16x16x32_f16(a, b, acc[ct], 0, 0, 0);
        }
    }
    __shared__ float sred[64][4];
    __shared__ float qred[64][4];
    #pragma unroll
    for (int ct = 0; ct < 4; ++ct) {
        int colb = ct * 16 + l16;
        int col = n0 + colb;
        float s = 0.f, q = 0.f;
        #pragma unroll
        for (int r = 0; r < 4; ++r) {
            int row = m0 + w * 16 + quad * 4 + r;
            bool ok = row < M;
            float v = ok ? acc[ct][r] : 0.f;
            if (ok && col < co) z[(size_t)row * co + col] = v;
            s += v; q += v * v;
        }
        s += __shfl_xor(s, 16, 64); q += __shfl_xor(q, 16, 64);
        s += __shfl_xor(s, 32, 64); q += __shfl_xor(q, 32, 64);
        if (quad == 0) { sred[colb][w] = s; qred[colb][w] = q; }
    }
    __syncthreads();
    if (tid < 64 && (n0 + tid) < co) {
        float s = sred[tid][0] + sred[tid][1] + sred[tid][2] + sred[tid][3];
        float q = qred[tid][0] + qred[tid][1] + qred[tid][2] + qred[tid][3];
        atomicAdd(&stats[n0 + tid], s);
        atomicAdd(&stats[co + n0 + tid], q);
    }
}

// ---------------- fused BN apply + relu + fp16 h out + next-layer xu (wave per node) ----------------
template<int V>
__global__ __launch_bounds__(256) void k_bnx(const float* __restrict__ z,
        const float* __restrict__ stats, const float* __restrict__ g,
        const float* __restrict__ b, const float* __restrict__ Un,
        _Float16* __restrict__ hout, float* __restrict__ xun, int n, int co) {
    int w = threadIdx.x >> 6, lane = threadIdx.x & 63;
    int node = blockIdx.x * 4 + w;
    if (node >= n) return;
    int c0 = lane * V;
    bool act = c0 < co;
    float invn = 1.f / (float)n;
    float hv[V];
    #pragma unroll
    for (int v = 0; v < V; ++v) hv[v] = 0.f;
    if (act) {
        const float* zp = z + (size_t)node * co + c0;
        float zv[V];
        if (V == 4) { float4 f = *(const float4*)zp; zv[0] = f.x; zv[1] = f.y; zv[2] = f.z; zv[3] = f.w; }
        else if (V == 2) { float2 f = *(const float2*)zp; zv[0] = f.x; zv[1] = f.y; }
        else zv[0] = zp[0];
        #pragma unroll
        for (int v = 0; v < V; ++v) {
            int cch = c0 + v;
            float mm = stats[cch] * invn;
            float vr = stats[co + cch] * invn - mm * mm;
            hv[v] = fmaxf((zv[v] - mm) * rsqrtf(vr + EPS) * g[cch] + b[cch], 0.f);
        }
        _Float16* hp = hout + (size_t)node * co + c0;
        if (V == 4) { half4 f = {(_Float16)hv[0], (_Float16)hv[1], (_Float16)hv[2], (_Float16)hv[3]}; *(half4*)hp = f; }
        else if (V == 2) { half2v f = {(_Float16)hv[0], (_Float16)hv[1]}; *(half2v*)hp = f; }
        else hp[0] = (_Float16)hv[0];
    }
    if (Un) {
        float p[8];
        #pragma unroll
        for (int hh = 0; hh < 8; ++hh) p[hh] = 0.f;
        if (act) {
            #pragma unroll
            for (int v = 0; v < V; ++v)
                #pragma unroll
                for (int hh = 0; hh < 8; ++hh) p[hh] += hv[v] * Un[(c0 + v) * 8 + hh];
        }
        #pragma unroll
        for (int hh = 0; hh < 8; ++hh) {
            #pragma unroll
            for (int off = 32; off; off >>= 1) p[hh] += __shfl_xor(p[hh], off, 64);
        }
        float mine = 0.f;
        #pragma unroll
        for (int hh = 0; hh < 8; ++hh) if (lane == hh) mine = p[hh];
        if (lane < 8) xun[node * 8 + lane] = mine;
    }
}

// ---------------- fused L5 BN + lin1(relu) + lin2: one wave per node ----------------
__global__ __launch_bounds__(256) void k_bnlin(const float* __restrict__ z,
        const float* __restrict__ stats, const float* __restrict__ g,
        const float* __restrict__ b, const float* __restrict__ W1,
        const float* __restrict__ b1, const float* __restrict__ W2,
        const float* __restrict__ b2, float* __restrict__ out, int n) {
    __shared__ float hbuf[4][128];
    int w = threadIdx.x >> 6, lane = threadIdx.x & 63;
    int node = blockIdx.x * 4 + w;
    if (node >= n) return;
    float invn = 1.f / (float)n;
    float2 zv = *(const float2*)(z + (size_t)node * 128 + lane * 2);
    float zr[2] = {zv.x, zv.y};
    #pragma unroll
    for (int v = 0; v < 2; ++v) {
        int c = lane * 2 + v;
        float mm = stats[c] * invn;
        float vr = stats[128 + c] * invn - mm * mm;
        hbuf[w][c] = fmaxf((zr[v] - mm) * rsqrtf(vr + EPS) * g[c] + b[c], 0.f);
    }
    float s = b1[lane];
    #pragma unroll 8
    for (int k = 0; k < 128; ++k) s += hbuf[w][k] * W1[k * 64 + lane];
    float r = fmaxf(s, 0.f);
    float p0 = r * W2[lane * 2];
    float p1 = r * W2[lane * 2 + 1];
    #pragma unroll
    for (int off = 32; off > 0; off >>= 1) {
        p0 += __shfl_down(p0, off, 64);
        p1 += __shfl_down(p1, off, 64);
    }
    if (lane == 0) {
        out[node * 2] = p0 + b2[0];
        out[node * 2 + 1] = p1 + b2[1];
    }
}

extern "C" void kernel_launch(void* const* d_in, const int* in_sizes, int n_in,
                              void* d_out, int out_size, void* d_ws, size_t ws_size,
                              hipStream_t stream) {
    const float* pos    = (const float*)d_in[0];
    const float* x      = (const float*)d_in[1];
    const int*   ei     = (const int*)d_in[2];
    const float* g0     = (const float*)d_in[3];
    const float* b0     = (const float*)d_in[4];
    const float* lin0_W = (const float*)d_in[5];
    const float* lin0_b = (const float*)d_in[6];
    const float* lin1_W = (const float*)d_in[43];
    const float* lin1_b = (const float*)d_in[44];
    const float* lin2_W = (const float*)d_in[45];
    const float* lin2_b = (const float*)d_in[46];

    int N = in_sizes[0] / 2;
    int E = in_sizes[2] / 2;
    int E2 = E + N;

    static const int CI[6]  = {16, 32, 64, 128, 256, 128};
    static const int CO[6]  = {32, 64, 128, 256, 128, 128};
    static const int COP[6] = {64, 64, 128, 256, 128, 128};
    static const int BPOFF[6] = {0, 8192, 24576, 90112, 352256, 614400};

    char* p = (char*)d_ws;
    auto alloc = [&](size_t bytes) -> char* {
        char* r = p;
        p += (bytes + 255) & ~(size_t)255;
        return r;
    };
    unsigned short* BpAll = (unsigned short*)alloc((size_t)PACK_TOTAL * 2);
    char* zr = alloc(((size_t)2 * N + 4 + 6 * 512) * 4);
    int*   deg      = (int*)zr;
    int*   fill     = deg + N;
    float* pstats   = (float*)(fill + N);
    float* statsAll = pstats + 4;
    size_t zr_bytes = ((size_t)2 * N + 4 + 6 * 512) * 4;

    int* row_ptr    = (int*)alloc(((size_t)N + 1) * 4);
    int* src_sorted = (int*)alloc((size_t)E2 * 4);
    float* xu       = (float*)alloc((size_t)N * 8 * 4);
    unsigned short* S = (unsigned short*)alloc((size_t)N * 2048 * 2);
    float* z        = (float*)alloc((size_t)N * 256 * 4);
    _Float16* hA    = (_Float16*)alloc((size_t)N * 256 * 2);
    _Float16* hB    = (_Float16*)alloc((size_t)N * 256 * 2);

    hipMemsetAsync(zr, 0, zr_bytes, stream);

    const int tpb = 256;
    int degBlocks = (E2 + tpb - 1) / tpb;
    int fillBlocks = degBlocks;
    int frontBlocks = (N + tpb - 1) / tpb;

    k_setup1<<<PACK_BLOCKS + degBlocks + 64, tpb, 0, stream>>>(
        (const float*)d_in[7], (const float*)d_in[13], (const float*)d_in[19],
        (const float*)d_in[25], (const float*)d_in[31], (const float*)d_in[37], BpAll,
        ei, deg, pos, pstats, E, N, degBlocks);
    k_scan<<<1, 1024, 0, stream>>>(deg, row_ptr, N);
    k_setup2<<<fillBlocks + frontBlocks, tpb, 0, stream>>>(
        ei, row_ptr, fill, src_sorted, pos, x, pstats, g0, b0, lin0_W, lin0_b,
        (const float*)d_in[8], hA, xu, E, N, fillBlocks);

    _Float16* hin = hA;
    _Float16* hout = hB;
    for (int L = 0; L < 6; ++L) {
        int ci = CI[L], co = CO[L], coP = COP[L];
        const float* Ch = (const float*)d_in[7 + L * 6 + 2];
        const float* gc = (const float*)d_in[7 + L * 6 + 4];
        const float* bc = (const float*)d_in[7 + L * 6 + 5];
        const float* Un = (L < 5) ? (const float*)d_in[7 + (L + 1) * 6 + 1] : nullptr;
        int K = HEADS * ci;
        float* statsL = statsAll + L * 512;

        int ggrid = (N + 3) / 4;
        if (ci == 16)       k_gather_small<2><<<ggrid, 256, 0, stream>>>(hin, xu, Ch, row_ptr, src_sorted, S, N);
        else if (ci == 32)  k_gather_small<4><<<ggrid, 256, 0, stream>>>(hin, xu, Ch, row_ptr, src_sorted, S, N);
        else if (ci == 64)  k_gather_big<1><<<ggrid, 256, 0, stream>>>(hin, xu, Ch, row_ptr, src_sorted, S, N, ci);
        else if (ci == 128) k_gather_big<2><<<ggrid, 256, 0, stream>>>(hin, xu, Ch, row_ptr, src_sorted, S, N, ci);
        else                k_gather_big<4><<<ggrid, 256, 0, stream>>>(hin, xu, Ch, row_ptr, src_sorted, S, N, ci);

        dim3 g((N + 63) / 64, coP / 64);
        k_gemm_stats<<<g, 256, 0, stream>>>(S, BpAll + BPOFF[L], z, statsL, N, K, co, coP / 16);

        int bgrid = (N + 3) / 4;
        if (L < 5) {
            if (co >= 256)      k_bnx<4><<<bgrid, 256, 0, stream>>>(z, statsL, gc, bc, Un, hout, xu, N, co);
            else if (co >= 128) k_bnx<2><<<bgrid, 256, 0, stream>>>(z, statsL, gc, bc, Un, hout, xu, N, co);
            else                k_bnx<1><<<bgrid, 256, 0, stream>>>(z, statsL, gc, bc, Un, hout, xu, N, co);
            _Float16* t = hin; hin = hout; hout = t;
        } else {
            k_bnlin<<<bgrid, 256, 0, stream>>>(z, statsL, gc, bc, lin1_W, lin1_b, lin2_W, lin2_b,
                                               (float*)d_out, N);
        }
    }
}

// Round 11
// 441.877 us; speedup vs baseline: 1.0169x; 1.0169x over previous
//
#include <hip/hip_runtime.h>
#include <hip/hip_bf16.h>
#include <math.h>

#define HEADS 8
#define EPS 1e-5f

typedef __attribute__((ext_vector_type(8))) _Float16 half8;
typedef __attribute__((ext_vector_type(4))) _Float16 half4;
typedef __attribute__((ext_vector_type(2))) _Float16 half2v;
typedef __attribute__((ext_vector_type(4))) float f32x4;

__device__ __forceinline__ unsigned short f2h(float f) {
    union { _Float16 h; unsigned short u; } v;
    v.h = (_Float16)f;
    return v.u;
}

#define PACK_TOTAL 745472
#define PACK_BLOCKS 2912   // PACK_TOTAL / 256

// ---------------- fused setup #1: weight-pack || degree-histogram || pos-stats ----------------
__global__ void k_setup1(const float* __restrict__ W0, const float* __restrict__ W1,
                         const float* __restrict__ W2, const float* __restrict__ W3,
                         const float* __restrict__ W4, const float* __restrict__ W5,
                         unsigned short* __restrict__ Bp,
                         const int* __restrict__ ei, int* __restrict__ deg,
                         const float* __restrict__ pos, float* __restrict__ pstats,
                         int E, int N, int degBlocks) {
    int b = blockIdx.x, tid = threadIdx.x;
    if (b < PACK_BLOCKS) {
        int idx = b * 256 + tid;
        const int CI[6]  = {16, 32, 64, 128, 256, 128};
        const int CO[6]  = {32, 64, 128, 256, 128, 128};
        const int COP[6] = {64, 64, 128, 256, 128, 128};
        const int OFF[7] = {0, 8192, 24576, 90112, 352256, 614400, 745472};
        int L = 0;
        while (idx >= OFF[L + 1]) ++L;
        const float* W = L == 0 ? W0 : L == 1 ? W1 : L == 2 ? W2 : L == 3 ? W3 : L == 4 ? W4 : W5;
        int rel = idx - OFF[L];
        int j = rel & 7;
        int lane = (rel >> 3) & 63;
        int t = rel >> 9;
        int nT = COP[L] >> 4;
        int nt = t % nT, kt = t / nT;
        int kk = kt * 32 + ((lane >> 4) << 3) + j;
        int c  = (nt << 4) + (lane & 15);
        int ci = CI[L], co = CO[L];
        float v = 0.f;
        if (c < co) {
            int h = kk / ci, ko = kk % ci;
            v = W[ko * (HEADS * co) + h * co + c];
        }
        Bp[idx] = f2h(v);
    } else if (b < PACK_BLOCKS + degBlocks) {
        int e = (b - PACK_BLOCKS) * 256 + tid;
        int E2 = E + N;
        if (e < E2) {
            int dst = (e < E) ? ei[E + e] : (e - E);
            atomicAdd(&deg[dst], 1);
        }
    } else {
        int gid = (b - PACK_BLOCKS - degBlocks) * 256 + tid;
        int stride = 64 * 256;
        float s0 = 0, s1 = 0, q0 = 0, q1 = 0;
        for (int i = gid; i < N; i += stride) {
            float a = pos[i * 2], bb = pos[i * 2 + 1];
            s0 += a; s1 += bb; q0 += a * a; q1 += bb * bb;
        }
        __shared__ float red[256][4];
        red[tid][0] = s0; red[tid][1] = s1; red[tid][2] = q0; red[tid][3] = q1;
        __syncthreads();
        for (int off = 128; off > 0; off >>= 1) {
            if (tid < off) {
                red[tid][0] += red[tid + off][0]; red[tid][1] += red[tid + off][1];
                red[tid][2] += red[tid + off][2]; red[tid][3] += red[tid + off][3];
            }
            __syncthreads();
        }
        if (tid == 0) {
            atomicAdd(&pstats[0], red[0][0]); atomicAdd(&pstats[1], red[0][1]);
            atomicAdd(&pstats[2], red[0][2]); atomicAdd(&pstats[3], red[0][3]);
        }
    }
}

__global__ void k_scan(const int* __restrict__ deg, int* __restrict__ row_ptr, int n) {
    __shared__ int part[1024];
    int t = threadIdx.x;
    int chunk = (n + 1023) >> 10;
    int begin = t * chunk;
    int end = begin + chunk;
    if (begin > n) begin = n;
    if (end > n) end = n;
    int s = 0;
    for (int i = begin; i < end; ++i) s += deg[i];
    part[t] = s;
    __syncthreads();
    for (int off = 1; off < 1024; off <<= 1) {
        int v = (t >= off) ? part[t - off] : 0;
        __syncthreads();
        part[t] += v;
        __syncthreads();
    }
    int run = (t == 0) ? 0 : part[t - 1];
    for (int i = begin; i < end; ++i) { row_ptr[i] = run; run += deg[i]; }
    if (t == 1023) row_ptr[n] = part[1023];
}

// ---------------- fused setup #2: CSR-fill || front ----------------
__global__ void k_setup2(const int* __restrict__ ei, const int* __restrict__ row_ptr,
                         int* __restrict__ fill, int* __restrict__ src_sorted,
                         const float* __restrict__ pos, const float* __restrict__ x,
                         const float* __restrict__ pstats, const float* __restrict__ g0,
                         const float* __restrict__ b0, const float* __restrict__ W,
                         const float* __restrict__ bias, const float* __restrict__ U0,
                         _Float16* __restrict__ out, float* __restrict__ xu0,
                         int E, int N, int fillBlocks) {
    int b = blockIdx.x, tid = threadIdx.x;
    if (b < fillBlocks) {
        int e = b * 256 + tid;
        int E2 = E + N;
        if (e < E2) {
            int srcv, dst;
            if (e < E) { srcv = ei[e]; dst = ei[E + e]; } else { srcv = e - E; dst = srcv; }
            int p = atomicAdd(&fill[dst], 1);
            src_sorted[row_ptr[dst] + p] = srcv;
        }
    } else {
        int i = (b - fillBlocks) * 256 + tid;
        if (i >= N) return;
        float invn = 1.0f / (float)N;
        float in4[4];
        #pragma unroll
        for (int j = 0; j < 2; ++j) {
            float m = pstats[j] * invn;
            float v = pstats[2 + j] * invn - m * m;
            in4[j] = (pos[i * 2 + j] - m) * rsqrtf(v + EPS) * g0[j] + b0[j];
        }
        in4[2] = x[i * 2]; in4[3] = x[i * 2 + 1];
        float o16[16];
        #pragma unroll
        for (int o = 0; o < 16; ++o) {
            float s = bias[o];
            #pragma unroll
            for (int j = 0; j < 4; ++j) s += in4[j] * W[j * 16 + o];
            o16[o] = fmaxf(s, 0.f);
            out[i * 16 + o] = (_Float16)o16[o];
        }
        #pragma unroll
        for (int hh = 0; hh < 8; ++hh) {
            float p = 0.f;
            #pragma unroll
            for (int k = 0; k < 16; ++k) p += o16[k] * U0[k * 8 + hh];
            xu0[i * 8 + hh] = p;
        }
    }
}

// ---- chunked in-wave softmax: lane computes q[8] for edge (base+lane), parks in LDS ----
__device__ __forceinline__ void chunk_softmax(const float* __restrict__ xu,
        const int* __restrict__ srcs, int base, int cnt, int lane,
        float4 xi0, float4 xi1, float4 c0, float4 c1, float dinv,
        float* __restrict__ qrow, int* __restrict__ srow) {
    if (lane < cnt) {
        int s = srcs[base + lane];
        float4 xs0 = *(const float4*)(xu + (size_t)s * 8);
        float4 xs1 = *(const float4*)(xu + (size_t)s * 8 + 4);
        float t[8];
        t[0] = xs0.x - xi0.x + c0.x; t[1] = xs0.y - xi0.y + c0.y;
        t[2] = xs0.z - xi0.z + c0.z; t[3] = xs0.w - xi0.w + c0.w;
        t[4] = xs1.x - xi1.x + c1.x; t[5] = xs1.y - xi1.y + c1.y;
        t[6] = xs1.z - xi1.z + c1.z; t[7] = xs1.w - xi1.w + c1.w;
        float mx = t[0];
        #pragma unroll
        for (int h = 1; h < 8; ++h) mx = fmaxf(mx, t[h]);
        float sum = 0.f;
        #pragma unroll
        for (int h = 0; h < 8; ++h) { t[h] = __expf(t[h] - mx); sum += t[h]; }
        float qs = dinv / sum;
        float4 q0 = {t[0] * qs, t[1] * qs, t[2] * qs, t[3] * qs};
        float4 q1 = {t[4] * qs, t[5] * qs, t[6] * qs, t[7] * qs};
        *(float4*)(qrow + lane * 8) = q0;
        *(float4*)(qrow + lane * 8 + 4) = q1;
        srow[lane] = s;
    }
}

// ---------------- gather (ci>=64): wave per node, fused softmax + inline BN(prev)+relu ----------------
// zin is prev layer's z (fp16). stats==null -> identity affine (L0, h0 already relu'd).
template<int V>
__global__ __launch_bounds__(256) void k_gather_big(const _Float16* __restrict__ zin,
        const float* __restrict__ stats, const float* __restrict__ g,
        const float* __restrict__ b,
        const float* __restrict__ xu, const float* __restrict__ chead,
        const int* __restrict__ row_ptr, const int* __restrict__ srcs,
        unsigned short* __restrict__ S, int n, int ci) {
    __shared__ float qbuf[4][64 * 8];
    __shared__ int   sbuf[4][64];
    int w = threadIdx.x >> 6, lane = threadIdx.x & 63;
    int i = blockIdx.x * 4 + w;
    if (i >= n) return;
    int rp0 = row_ptr[i], rp1 = row_ptr[i + 1];
    float dinv = 1.f / (float)(rp1 - rp0);
    float4 xi0 = *(const float4*)(xu + (size_t)i * 8);
    float4 xi1 = *(const float4*)(xu + (size_t)i * 8 + 4);
    float4 c0 = *(const float4*)chead;
    float4 c1 = *(const float4*)(chead + 4);
    int kb = lane * V;
    float sc[V], bo[V];
    if (stats) {
        float invn = 1.f / (float)n;
        #pragma unroll
        for (int v = 0; v < V; ++v) {
            int c = kb + v;
            float m = stats[c] * invn;
            float var = stats[ci + c] * invn - m * m;
            float s = g[c] * rsqrtf(var + EPS);
            sc[v] = s; bo[v] = b[c] - m * s;
        }
    } else {
        #pragma unroll
        for (int v = 0; v < V; ++v) { sc[v] = 1.f; bo[v] = 0.f; }
    }
    float acc[8][V];
    #pragma unroll
    for (int hh = 0; hh < 8; ++hh)
        #pragma unroll
        for (int v = 0; v < V; ++v) acc[hh][v] = 0.f;

    for (int base = rp0; base < rp1; base += 64) {
        int cnt = rp1 - base; if (cnt > 64) cnt = 64;
        chunk_softmax(xu, srcs, base, cnt, lane, xi0, xi1, c0, c1, dinv, qbuf[w], sbuf[w]);
        for (int j = 0; j < cnt; ++j) {
            int s = sbuf[w][j];
            const _Float16* h0 = zin + (size_t)s * ci + kb;
            float xv[V];
            if (V == 4) {
                half4 f = *(const half4*)h0;
                #pragma unroll
                for (int v = 0; v < 4; ++v) xv[v] = fmaxf((float)f[v] * sc[v] + bo[v], 0.f);
            } else if (V == 2) {
                half2v f = *(const half2v*)h0;
                #pragma unroll
                for (int v = 0; v < 2; ++v) xv[v] = fmaxf((float)f[v] * sc[v] + bo[v], 0.f);
            } else {
                xv[0] = fmaxf((float)h0[0] * sc[0] + bo[0], 0.f);
            }
            const float4* qa = (const float4*)(qbuf[w] + j * 8);
            float4 qa0 = qa[0], qa1 = qa[1];
            float qA[8] = {qa0.x, qa0.y, qa0.z, qa0.w, qa1.x, qa1.y, qa1.z, qa1.w};
            #pragma unroll
            for (int hh = 0; hh < 8; ++hh)
                #pragma unroll
                for (int v = 0; v < V; ++v) acc[hh][v] += qA[hh] * xv[v];
        }
    }
    #pragma unroll
    for (int hh = 0; hh < 8; ++hh) {
        unsigned short o[V];
        #pragma unroll
        for (int v = 0; v < V; ++v) o[v] = f2h(acc[hh][v]);
        unsigned short* sp = S + (size_t)i * 8 * ci + hh * ci + kb;
        if (V == 4)      *(ushort4*)sp = *(ushort4*)o;
        else if (V == 2) *(ushort2*)sp = *(ushort2*)o;
        else             sp[0] = o[0];
    }
}

// ---------------- gather (ci=8*V2<=32): head-split lanes, inline BN(prev)+relu ----------------
template<int V2>
__global__ __launch_bounds__(256) void k_gather_small(const _Float16* __restrict__ zin,
        const float* __restrict__ stats, const float* __restrict__ g,
        const float* __restrict__ b,
        const float* __restrict__ xu, const float* __restrict__ chead,
        const int* __restrict__ row_ptr, const int* __restrict__ srcs,
        unsigned short* __restrict__ S, int n) {
    const int ci = 8 * V2;
    __shared__ float qbuf[4][64 * 8];
    __shared__ int   sbuf[4][64];
    int w = threadIdx.x >> 6, lane = threadIdx.x & 63;
    int i = blockIdx.x * 4 + w;
    if (i >= n) return;
    int rp0 = row_ptr[i], rp1 = row_ptr[i + 1];
    float dinv = 1.f / (float)(rp1 - rp0);
    float4 xi0 = *(const float4*)(xu + (size_t)i * 8);
    float4 xi1 = *(const float4*)(xu + (size_t)i * 8 + 4);
    float4 c0 = *(const float4*)chead;
    float4 c1 = *(const float4*)(chead + 4);
    int hh = lane >> 3;
    int kb = (lane & 7) * V2;
    float sc[V2], bo[V2];
    if (stats) {
        float invn = 1.f / (float)n;
        #pragma unroll
        for (int v = 0; v < V2; ++v) {
            int c = kb + v;
            float m = stats[c] * invn;
            float var = stats[ci + c] * invn - m * m;
            float s = g[c] * rsqrtf(var + EPS);
            sc[v] = s; bo[v] = b[c] - m * s;
        }
    } else {
        #pragma unroll
        for (int v = 0; v < V2; ++v) { sc[v] = 1.f; bo[v] = 0.f; }
    }
    float acc[V2];
    #pragma unroll
    for (int v = 0; v < V2; ++v) acc[v] = 0.f;

    for (int base = rp0; base < rp1; base += 64) {
        int cnt = rp1 - base; if (cnt > 64) cnt = 64;
        chunk_softmax(xu, srcs, base, cnt, lane, xi0, xi1, c0, c1, dinv, qbuf[w], sbuf[w]);
        for (int j = 0; j < cnt; ++j) {
            int s = sbuf[w][j];
            const _Float16* h0 = zin + (size_t)s * ci + kb;
            float xv[V2];
            if (V2 == 4) {
                half4 f = *(const half4*)h0;
                #pragma unroll
                for (int v = 0; v < 4; ++v) xv[v] = fmaxf((float)f[v] * sc[v] + bo[v], 0.f);
            } else {
                half2v f = *(const half2v*)h0;
                #pragma unroll
                for (int v = 0; v < 2; ++v) xv[v] = fmaxf((float)f[v] * sc[v] + bo[v], 0.f);
            }
            float q0 = qbuf[w][j * 8 + hh];
            #pragma unroll
            for (int v = 0; v < V2; ++v) acc[v] += q0 * xv[v];
        }
    }
    unsigned short o[V2];
    #pragma unroll
    for (int v = 0; v < V2; ++v) o[v] = f2h(acc[v]);
    unsigned short* sp = S + (size_t)i * 8 * ci + hh * ci + kb;
    if (V2 == 4) *(ushort4*)sp = *(ushort4*)o;
    else         *(ushort2*)sp = *(ushort2*)o;
}

// ---------------- MFMA fp16 GEMM + fused BN-stats; z out fp16 ----------------
__global__ __launch_bounds__(256) void k_gemm_stats(const unsigned short* __restrict__ A,
        const unsigned short* __restrict__ Bp, _Float16* __restrict__ z,
        float* __restrict__ stats, int M, int K, int co, int nTtot) {
    int tid = threadIdx.x;
    int w = tid >> 6, lane = tid & 63;
    int quad = lane >> 4, l16 = lane & 15;
    int m0 = blockIdx.x * 64;
    int n0 = blockIdx.y * 64;
    int nt0 = n0 >> 4;
    int m = m0 + w * 16 + l16;
    int mc = m < M ? m : M - 1;
    const half8* Ap = (const half8*)(A + (size_t)mc * K) + quad;
    const half8* Bb = (const half8*)Bp;
    f32x4 acc[4] = {};
    int nsteps = K >> 5;
    for (int ks = 0; ks < nsteps; ++ks) {
        half8 a = Ap[ks * 4];
        long bbase = ((long)ks * nTtot + nt0) * 64 + lane;
        #pragma unroll
        for (int ct = 0; ct < 4; ++ct) {
            half8 b = Bb[bbase + ct * 64];
            acc[ct] = __builtin_amdgcn_mfma_f32_16x16x32_f16(a, b, acc[ct], 0, 0, 0);
        }
    }
    __shared__ float sred[64][4];
    __shared__ float qred[64][4];
    #pragma unroll
    for (int ct = 0; ct < 4; ++ct) {
        int colb = ct * 16 + l16;
        int col = n0 + colb;
        float s = 0.f, q = 0.f;
        #pragma unroll
        for (int r = 0; r < 4; ++r) {
            int row = m0 + w * 16 + quad * 4 + r;
            bool ok = row < M;
            float v = ok ? acc[ct][r] : 0.f;
            if (ok && col < co) z[(size_t)row * co + col] = (_Float16)v;
            s += v; q += v * v;
        }
        s += __shfl_xor(s, 16, 64); q += __shfl_xor(q, 16, 64);
        s += __shfl_xor(s, 32, 64); q += __shfl_xor(q, 32, 64);
        if (quad == 0) { sred[colb][w] = s; qred[colb][w] = q; }
    }
    __syncthreads();
    if (tid < 64 && (n0 + tid) < co) {
        float s = sred[tid][0] + sred[tid][1] + sred[tid][2] + sred[tid][3];
        float q = qred[tid][0] + qred[tid][1] + qred[tid][2] + qred[tid][3];
        atomicAdd(&stats[n0 + tid], s);
        atomicAdd(&stats[co + n0 + tid], q);
    }
}

// ---------------- xu-only epilogue: xu = relu(BN(z)) @ U_next (wave per node) ----------------
template<int V>
__global__ __launch_bounds__(256) void k_xu(const _Float16* __restrict__ z,
        const float* __restrict__ stats, const float* __restrict__ g,
        const float* __restrict__ b, const float* __restrict__ Un,
        float* __restrict__ xun, int n, int co) {
    int w = threadIdx.x >> 6, lane = threadIdx.x & 63;
    int node = blockIdx.x * 4 + w;
    if (node >= n) return;
    int c0 = lane * V;
    bool act = c0 < co;
    float invn = 1.f / (float)n;
    float p[8];
    #pragma unroll
    for (int hh = 0; hh < 8; ++hh) p[hh] = 0.f;
    if (act) {
        const _Float16* zp = z + (size_t)node * co + c0;
        float hv[V];
        #pragma unroll
        for (int v = 0; v < V; ++v) {
            int c = c0 + v;
            float m = stats[c] * invn;
            float var = stats[co + c] * invn - m * m;
            float s = g[c] * rsqrtf(var + EPS);
            hv[v] = fmaxf((float)zp[v] * s + (b[c] - m * s), 0.f);
        }
        #pragma unroll
        for (int v = 0; v < V; ++v)
            #pragma unroll
            for (int hh = 0; hh < 8; ++hh) p[hh] += hv[v] * Un[(c0 + v) * 8 + hh];
    }
    #pragma unroll
    for (int hh = 0; hh < 8; ++hh) {
        #pragma unroll
        for (int off = 32; off; off >>= 1) p[hh] += __shfl_xor(p[hh], off, 64);
    }
    float mine = 0.f;
    #pragma unroll
    for (int hh = 0; hh < 8; ++hh) if (lane == hh) mine = p[hh];
    if (lane < 8) xun[node * 8 + lane] = mine;
}

// ---------------- fused L5 BN + lin1(relu) + lin2: one wave per node (fp16 z) ----------------
__global__ __launch_bounds__(256) void k_bnlin(const _Float16* __restrict__ z,
        const float* __restrict__ stats, const float* __restrict__ g,
        const float* __restrict__ b, const float* __restrict__ W1,
        const float* __restrict__ b1, const float* __restrict__ W2,
        const float* __restrict__ b2, float* __restrict__ out, int n) {
    __shared__ float hbuf[4][128];
    int w = threadIdx.x >> 6, lane = threadIdx.x & 63;
    int node = blockIdx.x * 4 + w;
    if (node >= n) return;
    float invn = 1.f / (float)n;
    half2v zv = *(const half2v*)(z + (size_t)node * 128 + lane * 2);
    #pragma unroll
    for (int v = 0; v < 2; ++v) {
        int c = lane * 2 + v;
        float mm = stats[c] * invn;
        float vr = stats[128 + c] * invn - mm * mm;
        float s = g[c] * rsqrtf(vr + EPS);
        hbuf[w][c] = fmaxf((float)zv[v] * s + (b[c] - mm * s), 0.f);
    }
    float s = b1[lane];
    #pragma unroll 8
    for (int k = 0; k < 128; ++k) s += hbuf[w][k] * W1[k * 64 + lane];
    float r = fmaxf(s, 0.f);
    float p0 = r * W2[lane * 2];
    float p1 = r * W2[lane * 2 + 1];
    #pragma unroll
    for (int off = 32; off > 0; off >>= 1) {
        p0 += __shfl_down(p0, off, 64);
        p1 += __shfl_down(p1, off, 64);
    }
    if (lane == 0) {
        out[node * 2] = p0 + b2[0];
        out[node * 2 + 1] = p1 + b2[1];
    }
}

extern "C" void kernel_launch(void* const* d_in, const int* in_sizes, int n_in,
                              void* d_out, int out_size, void* d_ws, size_t ws_size,
                              hipStream_t stream) {
    const float* pos    = (const float*)d_in[0];
    const float* x      = (const float*)d_in[1];
    const int*   ei     = (const int*)d_in[2];
    const float* g0     = (const float*)d_in[3];
    const float* b0     = (const float*)d_in[4];
    const float* lin0_W = (const float*)d_in[5];
    const float* lin0_b = (const float*)d_in[6];
    const float* lin1_W = (const float*)d_in[43];
    const float* lin1_b = (const float*)d_in[44];
    const float* lin2_W = (const float*)d_in[45];
    const float* lin2_b = (const float*)d_in[46];

    int N = in_sizes[0] / 2;
    int E = in_sizes[2] / 2;
    int E2 = E + N;

    static const int CI[6]  = {16, 32, 64, 128, 256, 128};
    static const int CO[6]  = {32, 64, 128, 256, 128, 128};
    static const int COP[6] = {64, 64, 128, 256, 128, 128};
    static const int BPOFF[6] = {0, 8192, 24576, 90112, 352256, 614400};

    char* p = (char*)d_ws;
    auto alloc = [&](size_t bytes) -> char* {
        char* r = p;
        p += (bytes + 255) & ~(size_t)255;
        return r;
    };
    unsigned short* BpAll = (unsigned short*)alloc((size_t)PACK_TOTAL * 2);
    char* zr = alloc(((size_t)2 * N + 4 + 6 * 512) * 4);
    int*   deg      = (int*)zr;
    int*   fill     = deg + N;
    float* pstats   = (float*)(fill + N);
    float* statsAll = pstats + 4;
    size_t zr_bytes = ((size_t)2 * N + 4 + 6 * 512) * 4;

    int* row_ptr    = (int*)alloc(((size_t)N + 1) * 4);
    int* src_sorted = (int*)alloc((size_t)E2 * 4);
    float* xu       = (float*)alloc((size_t)N * 8 * 4);
    unsigned short* S = (unsigned short*)alloc((size_t)N * 2048 * 2);
    _Float16* z     = (_Float16*)alloc((size_t)N * 256 * 2);
    _Float16* hA    = (_Float16*)alloc((size_t)N * 16 * 2);

    hipMemsetAsync(zr, 0, zr_bytes, stream);

    const int tpb = 256;
    int degBlocks = (E2 + tpb - 1) / tpb;
    int fillBlocks = degBlocks;
    int frontBlocks = (N + tpb - 1) / tpb;

    k_setup1<<<PACK_BLOCKS + degBlocks + 64, tpb, 0, stream>>>(
        (const float*)d_in[7], (const float*)d_in[13], (const float*)d_in[19],
        (const float*)d_in[25], (const float*)d_in[31], (const float*)d_in[37], BpAll,
        ei, deg, pos, pstats, E, N, degBlocks);
    k_scan<<<1, 1024, 0, stream>>>(deg, row_ptr, N);
    k_setup2<<<fillBlocks + frontBlocks, tpb, 0, stream>>>(
        ei, row_ptr, fill, src_sorted, pos, x, pstats, g0, b0, lin0_W, lin0_b,
        (const float*)d_in[8], hA, xu, E, N, fillBlocks);

    for (int L = 0; L < 6; ++L) {
        int ci = CI[L], co = CO[L], coP = COP[L];
        const float* Ch = (const float*)d_in[7 + L * 6 + 2];
        const float* gc = (const float*)d_in[7 + L * 6 + 4];
        const float* bc = (const float*)d_in[7 + L * 6 + 5];
        const float* Un = (L < 5) ? (const float*)d_in[7 + (L + 1) * 6 + 1] : nullptr;
        int K = HEADS * ci;
        float* statsL = statsAll + L * 512;

        // gather reads prev layer's features: L0 -> hA (identity affine), L>=1 -> z + BN(L-1)
        const _Float16* zin = (L == 0) ? hA : z;
        const float* pstatsL = (L == 0) ? nullptr : statsAll + (L - 1) * 512;
        const float* gPrev   = (L == 0) ? nullptr : (const float*)d_in[7 + (L - 1) * 6 + 4];
        const float* bPrev   = (L == 0) ? nullptr : (const float*)d_in[7 + (L - 1) * 6 + 5];

        int ggrid = (N + 3) / 4;
        if (ci == 16)       k_gather_small<2><<<ggrid, 256, 0, stream>>>(zin, pstatsL, gPrev, bPrev, xu, Ch, row_ptr, src_sorted, S, N);
        else if (ci == 32)  k_gather_small<4><<<ggrid, 256, 0, stream>>>(zin, pstatsL, gPrev, bPrev, xu, Ch, row_ptr, src_sorted, S, N);
        else if (ci == 64)  k_gather_big<1><<<ggrid, 256, 0, stream>>>(zin, pstatsL, gPrev, bPrev, xu, Ch, row_ptr, src_sorted, S, N, ci);
        else if (ci == 128) k_gather_big<2><<<ggrid, 256, 0, stream>>>(zin, pstatsL, gPrev, bPrev, xu, Ch, row_ptr, src_sorted, S, N, ci);
        else                k_gather_big<4><<<ggrid, 256, 0, stream>>>(zin, pstatsL, gPrev, bPrev, xu, Ch, row_ptr, src_sorted, S, N, ci);

        dim3 g((N + 63) / 64, coP / 64);
        k_gemm_stats<<<g, 256, 0, stream>>>(S, BpAll + BPOFF[L], z, statsL, N, K, co, coP / 16);

        int bgrid = (N + 3) / 4;
        if (L < 5) {
            if (co >= 256)      k_xu<4><<<bgrid, 256, 0, stream>>>(z, statsL, gc, bc, Un, xu, N, co);
            else if (co >= 128) k_xu<2><<<bgrid, 256, 0, stream>>>(z, statsL, gc, bc, Un, xu, N, co);
            else                k_xu<1><<<bgrid, 256, 0, stream>>>(z, statsL, gc, bc, Un, xu, N, co);
        } else {
            k_bnlin<<<bgrid, 256, 0, stream>>>(z, statsL, gc, bc, lin1_W, lin1_b, lin2_W, lin2_b,
                                               (float*)d_out, N);
        }
    }
}